// Round 11
// baseline (152.643 us; speedup 1.0000x reference)
//
#include <hip/hip_runtime.h>

typedef unsigned short u16;
typedef unsigned int u32;
typedef short bf16x8 __attribute__((ext_vector_type(8)));
typedef float f32x4 __attribute__((ext_vector_type(4)));

#define HH 128

__device__ __forceinline__ u16 f2bf(float f) {
  u32 u = __float_as_uint(f);
  u += 0x7fffu + ((u >> 16) & 1u);  // round-to-nearest-even
  return (u16)(u >> 16);
}
__device__ __forceinline__ u32 pack2(float a, float b) {
  return (u32)f2bf(a) | ((u32)f2bf(b) << 16);
}
__device__ __forceinline__ float bf2f(u16 h) {
  return __uint_as_float(((u32)h) << 16);
}

// ---------------------------------------------------------------------------
// Pre-pass: fused W_comb (bf16), chunk-transposed + bank-swizzled, into d_ws.
// Chunk index (((q*16+kc)*512+n)*4+p) holds W[k = kc*32 + lq*8 + j][col n],
// lq = p ^ (n&3) ^ ((n>>2)&3).
// Fused: k<384 -> W_cat[k][q*512+n]; k>=384 -> (n<128 ? 0 : W_exp[k-384][q*384+n-128])
// ---------------------------------------------------------------------------
__global__ __launch_bounds__(256) void prep_w(const float* __restrict__ Wcat,
                                              const float* __restrict__ Wexp,
                                              u16* __restrict__ Wc) {
  const int bx = blockIdx.x;      // 512 blocks: ((q*16+kc)*8 + nt)
  const int nt = bx & 7;
  const int kc = (bx >> 3) & 15;
  const int q = bx >> 7;
  __shared__ u16 T[32 * 72];      // [k-in-chunk][64 cols], stride 72 (pad)

  const int tid = threadIdx.x;
  const int r = tid >> 3;
  const int c8 = (tid & 7) * 8;
  float v[8];
  if (kc < 12) {
    const float* src =
        Wcat + (size_t)(kc * 32 + r) * 2048 + q * 512 + nt * 64 + c8;
    float4 a = *(const float4*)src;
    float4 b = *(const float4*)(src + 4);
    v[0] = a.x; v[1] = a.y; v[2] = a.z; v[3] = a.w;
    v[4] = b.x; v[5] = b.y; v[6] = b.z; v[7] = b.w;
  } else if (nt >= 2) {
    const float* src = Wexp + (size_t)((kc - 12) * 32 + r) * 1536 + q * 384 +
                       nt * 64 + c8 - 128;
    float4 a = *(const float4*)src;
    float4 b = *(const float4*)(src + 4);
    v[0] = a.x; v[1] = a.y; v[2] = a.z; v[3] = a.w;
    v[4] = b.x; v[5] = b.y; v[6] = b.z; v[7] = b.w;
  } else {
#pragma unroll
    for (int j = 0; j < 8; ++j) v[j] = 0.f;
  }
  uint4 pk;
  pk.x = pack2(v[0], v[1]);
  pk.y = pack2(v[2], v[3]);
  pk.z = pack2(v[4], v[5]);
  pk.w = pack2(v[6], v[7]);
  *(uint4*)&T[r * 72 + c8] = pk;
  __syncthreads();

  const int p = tid & 3;
  const int nl = tid >> 2;  // 0..63 local col
  const int lq = p ^ (nl & 3) ^ ((nl >> 2) & 3);
  u16 w[8];
#pragma unroll
  for (int j = 0; j < 8; ++j) w[j] = T[(lq * 8 + j) * 72 + nl];
  uint4 o;
  o.x = (u32)w[0] | ((u32)w[1] << 16);
  o.y = (u32)w[2] | ((u32)w[3] << 16);
  o.z = (u32)w[4] | ((u32)w[5] << 16);
  o.w = (u32)w[6] | ((u32)w[7] << 16);
  const size_t idx = ((size_t)((q * 16 + kc) * 512) + nt * 64 + nl) * 4 + p;
  ((uint4*)Wc)[idx] = o;
}

// ---------------------------------------------------------------------------
// Fused GEMM + gate epilogue — barrier-free K-loop, 8-wave blocks.
// Block: (b,q) x 64-row tile x FULL 128-h slab. 8 waves; wave w owns columns
// {gg*128 + w*16 + c}, gg 0..3 (softmax-coupled, register-local).
// A (64x512 bf16, 64 KB) staged once with ONE barrier, shared by all 8 waves;
// B streamed global->VGPR (W_comb L2-resident), 1-deep prefetch.
// 2 blocks/CU (128 KB LDS) = 16 waves/CU = 4 waves/SIMD.
// R1: B addressing = uniform SGPR base + u32 byte offsets (saves ~4-6 VGPR);
//     af loaded in pairs (halves af liveness); s_setprio around MFMA clusters.
// A LDS layout: [kc][row][32k], physical octet p = o ^ s(row) ^ (kc>>2),
// s(row) = (row&3)^((row>>2)&3).
// ---------------------------------------------------------------------------
__global__ __launch_bounds__(512, 4) void fused_gate(
    const float* __restrict__ CNN, const float* __restrict__ gaz,
    const float* __restrict__ gazb, const float* __restrict__ gm,
    const float* __restrict__ exper, const u16* __restrict__ Wc,
    const float* __restrict__ bcat, const float* __restrict__ bexp,
    float* __restrict__ out) {
  __shared__ u16 Abuf[16 * 64 * 32];  // 64 KB

  const int tid = threadIdx.x;
  const int lane = tid & 63;
  const int wave = tid >> 6;  // 0..7
  const int bx = blockIdx.x;  // 1024: grp*8 + tile
  const int tile = bx & 7;
  const int grp = bx >> 3;
  const int b = grp >> 2;
  const int q = grp & 3;
  const int s_base = tile * 64;

  // ---- stage A: wave pair (sel = wave>>1) loads source sel; wave&1 picks
  //      the 32-row half. Each wave: 32 rows x 128 feats (16 KB fp32).
  const int sel = wave >> 1;
  const float* src_w =
      (sel == 0) ? CNN + (size_t)(b * 2048 + q * 512 + s_base) * HH
      : (sel == 1) ? (((q & 1) ? gazb : gaz) + (size_t)(b * 512 + s_base) * HH)
      : (sel == 2) ? gm + (size_t)(b * 512 + s_base) * HH
                   : exper + (size_t)(b * 512 + s_base) * HH;
#pragma unroll
  for (int t = 0; t < 8; ++t) {
    const int s = t * 64 + lane;            // 0..511
    const int row = (wave & 1) * 32 + (s >> 4);
    const int oct = s & 15;                 // 16B-octet within 128-feat row
    const float* sp = src_w + (size_t)row * HH + oct * 8;
    float4 f0 = *(const float4*)sp;
    float4 f1 = *(const float4*)(sp + 4);
    uint4 pk;
    pk.x = pack2(f0.x, f0.y);
    pk.y = pack2(f0.z, f0.w);
    pk.z = pack2(f1.x, f1.y);
    pk.w = pack2(f1.z, f1.w);
    const int kc = sel * 4 + (oct >> 2);
    const int o = oct & 3;
    const int ph = o ^ ((row & 3) ^ ((row >> 2) & 3)) ^ sel;  // kc>>2 == sel
    *(uint4*)&Abuf[(kc * 64 + row) * 32 + ph * 8] = pk;
  }
  __syncthreads();

  // ---- K-loop: barrier-free, B 1-deep prefetch from global (L2) ----
  const int l15 = lane & 15;
  const int quad = lane >> 4;
  const int sl = (l15 & 3) ^ ((l15 >> 2) & 3);
  const int physB = quad ^ sl;

  // q-slice base is wave-uniform -> SGPR; per-lane state is 4 u32 offsets.
  // u16 addr = q*262144 + kc*16384 + (n*4+physB)*8  (byte: x2)
  const char* __restrict__ Wq = (const char*)(Wc + (size_t)q * 262144);
  u32 offb[4];
#pragma unroll
  for (int gg = 0; gg < 4; ++gg) {
    const int n = gg * 128 + wave * 16 + l15;
    offb[gg] = (u32)((n * 4 + physB) * 16);
  }

  f32x4 acc[4][4];
#pragma unroll
  for (int rt = 0; rt < 4; ++rt)
#pragma unroll
    for (int gg = 0; gg < 4; ++gg) acc[rt][gg] = (f32x4)0.f;

  bf16x8 bcur[4], bnxt[4];
#pragma unroll
  for (int gg = 0; gg < 4; ++gg)
    bcur[gg] = *(const bf16x8*)(Wq + offb[gg]);

#pragma unroll
  for (int kc = 0; kc < 16; ++kc) {
    if (kc < 15) {
      const u32 kb = (u32)(kc + 1) * 32768u;
#pragma unroll
      for (int gg = 0; gg < 4; ++gg)
        bnxt[gg] = *(const bf16x8*)(Wq + (kb + offb[gg]));
    }
    const int pa = (quad ^ sl ^ (kc >> 2)) * 8;
    const u16* ab = &Abuf[(kc * 64 + l15) * 32 + pa];
    bf16x8 af0 = *(const bf16x8*)(ab);
    bf16x8 af1 = *(const bf16x8*)(ab + 16 * 32);
    __builtin_amdgcn_s_setprio(1);
#pragma unroll
    for (int gg = 0; gg < 4; ++gg)
      acc[0][gg] = __builtin_amdgcn_mfma_f32_16x16x32_bf16(af0, bcur[gg],
                                                           acc[0][gg], 0, 0, 0);
#pragma unroll
    for (int gg = 0; gg < 4; ++gg)
      acc[1][gg] = __builtin_amdgcn_mfma_f32_16x16x32_bf16(af1, bcur[gg],
                                                           acc[1][gg], 0, 0, 0);
    __builtin_amdgcn_s_setprio(0);
    bf16x8 af2 = *(const bf16x8*)(ab + 32 * 32);
    bf16x8 af3 = *(const bf16x8*)(ab + 48 * 32);
    __builtin_amdgcn_s_setprio(1);
#pragma unroll
    for (int gg = 0; gg < 4; ++gg)
      acc[2][gg] = __builtin_amdgcn_mfma_f32_16x16x32_bf16(af2, bcur[gg],
                                                           acc[2][gg], 0, 0, 0);
#pragma unroll
    for (int gg = 0; gg < 4; ++gg)
      acc[3][gg] = __builtin_amdgcn_mfma_f32_16x16x32_bf16(af3, bcur[gg],
                                                           acc[3][gg], 0, 0, 0);
    __builtin_amdgcn_s_setprio(0);
#pragma unroll
    for (int gg = 0; gg < 4; ++gg) bcur[gg] = bnxt[gg];
  }

  // ---- epilogue: tanh / sigmoid / softmax-of-3 / weighted state sum ----
  const float* bcq = bcat + q * 512;
  const float* beq = bexp + q * 384;
  const size_t outbase = (size_t)((q * 32 + b) * 512 + s_base) * HH;
  const int h = wave * 16 + l15;  // 0..127
  const float bc0 = bcq[h];
  const float bc1 = bcq[128 + h];
  const float bc2 = bcq[256 + h];
  const float bc3 = bcq[384 + h];
  const float be1 = beq[h];
  const float be2 = beq[128 + h];
  const float be3 = beq[256 + h];
  const int kcc = h >> 5;         // CNN chunk (0..3)
  const int kce = 12 + (h >> 5);  // exper chunk (12..15)
  const int oh = (h >> 3) & 3;
  const int he = h & 7;
#pragma unroll
  for (int rt = 0; rt < 4; ++rt) {
#pragma unroll
    for (int r = 0; r < 4; ++r) {
      const int row = rt * 16 + quad * 4 + r;
      const int srw = (row & 3) ^ ((row >> 2) & 3);
      const float cnn = bf2f(Abuf[(kcc * 64 + row) * 32 + (oh ^ srw) * 8 + he]);
      const float ex =
          bf2f(Abuf[(kce * 64 + row) * 32 + (oh ^ srw ^ 3) * 8 + he]);
      const float c0 = acc[rt][0][r] + bc0;
      const float p1 = acc[rt][1][r] + bc1 + be1;
      const float p2 = acc[rt][2][r] + bc2 + be2;
      const float p3 = acc[rt][3][r] + bc3 + be3;
      const float e2c = __expf(2.f * c0);
      const float ns = 1.f - 2.f * __builtin_amdgcn_rcpf(e2c + 1.f);  // tanh
      const float g1 = __builtin_amdgcn_rcpf(1.f + __expf(-p1));
      const float g2 = __builtin_amdgcn_rcpf(1.f + __expf(-p2));
      const float g3 = __builtin_amdgcn_rcpf(1.f + __expf(-p3));
      const float e1 = __expf(g1);
      const float e2 = __expf(g2);
      const float e3 = __expf(g3);
      const float inv = __builtin_amdgcn_rcpf(e1 + e2 + e3);
      out[outbase + (size_t)row * HH + h] = (e1 * ns + e2 * cnn + e3 * ex) * inv;
    }
  }
}

extern "C" void kernel_launch(void* const* d_in, const int* in_sizes, int n_in,
                              void* d_out, int out_size, void* d_ws, size_t ws_size,
                              hipStream_t stream) {
  const float* CNN = (const float*)d_in[0];
  const float* gaz = (const float*)d_in[1];
  const float* gazb = (const float*)d_in[2];
  const float* gm = (const float*)d_in[3];
  const float* exper = (const float*)d_in[4];
  const float* Wcat = (const float*)d_in[5];
  const float* bcat = (const float*)d_in[6];
  const float* Wexp = (const float*)d_in[7];
  const float* bexp = (const float*)d_in[8];
  u16* Wc = (u16*)d_ws;  // 2 MB fused bf16 weights

  prep_w<<<512, 256, 0, stream>>>(Wcat, Wexp, Wc);
  fused_gate<<<1024, 512, 0, stream>>>(CNN, gaz, gazb, gm, exper, Wc, bcat,
                                       bexp, (float*)d_out);
}

// Round 14
// 150.683 us; speedup vs baseline: 1.0130x; 1.0130x over previous
//
#include <hip/hip_runtime.h>

typedef unsigned short u16;
typedef unsigned int u32;
typedef short bf16x8 __attribute__((ext_vector_type(8)));
typedef float f32x4 __attribute__((ext_vector_type(4)));

#define HH 128

__device__ __forceinline__ u16 f2bf(float f) {
  u32 u = __float_as_uint(f);
  u += 0x7fffu + ((u >> 16) & 1u);  // round-to-nearest-even
  return (u16)(u >> 16);
}
__device__ __forceinline__ u32 pack2(float a, float b) {
  return (u32)f2bf(a) | ((u32)f2bf(b) << 16);
}
__device__ __forceinline__ float bf2f(u16 h) {
  return __uint_as_float(((u32)h) << 16);
}
__device__ __forceinline__ u32 cvtpk(float lo, float hi) {
  u32 r;
  asm("v_cvt_pk_bf16_f32 %0, %1, %2" : "=v"(r) : "v"(lo), "v"(hi));
  return r;
}

// ---------------------------------------------------------------------------
// Pre-pass: fused W_comb (bf16), chunk-transposed + bank-swizzled, into d_ws.
// Chunk index (((q*16+kc)*512+n)*4+p) holds W[k = kc*32 + lq*8 + j][col n],
// lq = p ^ (n&3) ^ ((n>>2)&3).
// Fused: k<384 -> W_cat[k][q*512+n]; k>=384 -> (n<128 ? 0 : W_exp[k-384][q*384+n-128])
// ---------------------------------------------------------------------------
__global__ __launch_bounds__(256) void prep_w(const float* __restrict__ Wcat,
                                              const float* __restrict__ Wexp,
                                              u16* __restrict__ Wc) {
  const int bx = blockIdx.x;      // 512 blocks: ((q*16+kc)*8 + nt)
  const int nt = bx & 7;
  const int kc = (bx >> 3) & 15;
  const int q = bx >> 7;
  __shared__ u16 T[32 * 72];      // [k-in-chunk][64 cols], stride 72 (pad)

  const int tid = threadIdx.x;
  const int r = tid >> 3;
  const int c8 = (tid & 7) * 8;
  float v[8];
  if (kc < 12) {
    const float* src =
        Wcat + (size_t)(kc * 32 + r) * 2048 + q * 512 + nt * 64 + c8;
    float4 a = *(const float4*)src;
    float4 b = *(const float4*)(src + 4);
    v[0] = a.x; v[1] = a.y; v[2] = a.z; v[3] = a.w;
    v[4] = b.x; v[5] = b.y; v[6] = b.z; v[7] = b.w;
  } else if (nt >= 2) {
    const float* src = Wexp + (size_t)((kc - 12) * 32 + r) * 1536 + q * 384 +
                       nt * 64 + c8 - 128;
    float4 a = *(const float4*)src;
    float4 b = *(const float4*)(src + 4);
    v[0] = a.x; v[1] = a.y; v[2] = a.z; v[3] = a.w;
    v[4] = b.x; v[5] = b.y; v[6] = b.z; v[7] = b.w;
  } else {
#pragma unroll
    for (int j = 0; j < 8; ++j) v[j] = 0.f;
  }
  uint4 pk;
  pk.x = pack2(v[0], v[1]);
  pk.y = pack2(v[2], v[3]);
  pk.z = pack2(v[4], v[5]);
  pk.w = pack2(v[6], v[7]);
  *(uint4*)&T[r * 72 + c8] = pk;
  __syncthreads();

  const int p = tid & 3;
  const int nl = tid >> 2;  // 0..63 local col
  const int lq = p ^ (nl & 3) ^ ((nl >> 2) & 3);
  u16 w[8];
#pragma unroll
  for (int j = 0; j < 8; ++j) w[j] = T[(lq * 8 + j) * 72 + nl];
  uint4 o;
  o.x = (u32)w[0] | ((u32)w[1] << 16);
  o.y = (u32)w[2] | ((u32)w[3] << 16);
  o.z = (u32)w[4] | ((u32)w[5] << 16);
  o.w = (u32)w[6] | ((u32)w[7] << 16);
  const size_t idx = ((size_t)((q * 16 + kc) * 512) + nt * 64 + nl) * 4 + p;
  ((uint4*)Wc)[idx] = o;
}

// ---------------------------------------------------------------------------
// R2: 128-row tiles, K split into 2 halves with 2x64KB LDS double-buffer.
// 512 blocks = (b,q) x 4 tiles of 128 rows. 8 waves; wave w owns cols
// {gg*128 + w*16 + c}. acc[8][4] (128 AGPR). 1 block/CU (256-VGPR budget).
// Half0 (CNN|gaz) staged up front; half1 (gm|exper) staged INSIDE K1's
// kc-loop (loads at kc start, ds_write after MFMAs) -> latency hidden.
// B traffic halves vs 64-row tiles: 268 MB L2 (~46% of ceiling).
// A LDS layout per buffer: [slot<8][row<128][32k], phys octet
// ph = o ^ s(row) ^ (kc_global>>2), s(row)=(row&3)^((row>>2)&3).
// Epilogue: cnn re-read from global fp32 (L2-hot); exper from buf1.
// ---------------------------------------------------------------------------
__global__ __launch_bounds__(512, 2) void fused_gate(
    const float* __restrict__ CNN, const float* __restrict__ gaz,
    const float* __restrict__ gazb, const float* __restrict__ gm,
    const float* __restrict__ exper, const u16* __restrict__ Wc,
    const float* __restrict__ bcat, const float* __restrict__ bexp,
    float* __restrict__ out) {
  __shared__ u16 Abuf[2][8 * 128 * 32];  // 2 x 64 KB

  const int tid = threadIdx.x;
  const int lane = tid & 63;
  const int wave = tid >> 6;  // 0..7
  const int bx = blockIdx.x;  // 512: grp*4 + tile
  const int tile = bx & 3;
  const int grp = bx >> 2;
  const int b = grp >> 2;
  const int q = grp & 3;
  const int s_base = tile * 128;

  // staging roles: sel2 = wave>>2 picks source within the half; rg = wave&3
  // picks the 32-row group. half0: sel2 0->CNN, 1->gaz/gazb. half1: 0->gm, 1->exper.
  const int sel2 = wave >> 2;
  const int rg = wave & 3;
  const float* srcA0 =
      (sel2 == 0) ? CNN + (size_t)(b * 2048 + q * 512 + s_base) * HH
                  : (((q & 1) ? gazb : gaz) + (size_t)(b * 512 + s_base) * HH);
  const float* srcA1 =
      (sel2 == 0) ? gm + (size_t)(b * 512 + s_base) * HH
                  : exper + (size_t)(b * 512 + s_base) * HH;

  // ---- stage half0 (feats 0..255 = kc 0..7) into buf0 ----
#pragma unroll
  for (int t = 0; t < 8; ++t) {
    const int srow = rg * 32 + t * 4 + (lane >> 4);
    const int oct = lane & 15;  // 8-feat octet within 128-feat source row
    const float* sp = srcA0 + (size_t)srow * HH + oct * 8;
    float4 f0 = *(const float4*)sp;
    float4 f1 = *(const float4*)(sp + 4);
    uint4 pk;
    pk.x = cvtpk(f0.x, f0.y);
    pk.y = cvtpk(f0.z, f0.w);
    pk.z = cvtpk(f1.x, f1.y);
    pk.w = cvtpk(f1.z, f1.w);
    const int kcl = sel2 * 4 + (oct >> 2);  // == kc_global for half0
    const int srw = (srow & 3) ^ ((srow >> 2) & 3);
    const int ph = (oct & 3) ^ srw ^ ((kcl >> 2) & 3);
    *(uint4*)&Abuf[0][(kcl * 128 + srow) * 32 + ph * 8] = pk;
  }
  __syncthreads();

  // ---- K-loop setup (B scheme identical to verified kernel) ----
  const int l15 = lane & 15;
  const int quad = lane >> 4;
  const int sl = (l15 & 3) ^ ((l15 >> 2) & 3);
  const int physB = quad ^ sl;
  const char* __restrict__ Wq = (const char*)(Wc + (size_t)q * 262144);
  u32 offb[4];
#pragma unroll
  for (int gg = 0; gg < 4; ++gg) {
    const int n = gg * 128 + wave * 16 + l15;
    offb[gg] = (u32)((n * 4 + physB) * 16);
  }

  f32x4 acc[8][4];
#pragma unroll
  for (int rt = 0; rt < 8; ++rt)
#pragma unroll
    for (int gg = 0; gg < 4; ++gg) acc[rt][gg] = (f32x4)0.f;

  bf16x8 bcur[4], bnxt[4];
#pragma unroll
  for (int gg = 0; gg < 4; ++gg) bcur[gg] = *(const bf16x8*)(Wq + offb[gg]);

  // ---- K1: kc 0..7 on buf0, half1 staging interleaved ----
#pragma unroll
  for (int kc = 0; kc < 8; ++kc) {
    // (1) issue half1 stage loads for this kc early — land during MFMAs
    const int srow = rg * 32 + kc * 4 + (lane >> 4);
    const int oct = lane & 15;
    const float* sp = srcA1 + (size_t)srow * HH + oct * 8;
    float4 f0 = *(const float4*)sp;
    float4 f1 = *(const float4*)(sp + 4);
    // (2) B prefetch
    if (kc < 7) {
      const u32 kb = (u32)(kc + 1) * 32768u;
#pragma unroll
      for (int gg = 0; gg < 4; ++gg)
        bnxt[gg] = *(const bf16x8*)(Wq + (kb + offb[gg]));
    }
    // (3) MFMA on buf0
    const int pa = (quad ^ sl ^ ((kc >> 2) & 3)) * 8;
    const u16* ab = &Abuf[0][(kc * 128 + l15) * 32 + pa];
#pragma unroll
    for (int pr = 0; pr < 4; ++pr) {
      bf16x8 afa = *(const bf16x8*)(ab + (2 * pr) * 16 * 32);
      bf16x8 afb = *(const bf16x8*)(ab + (2 * pr + 1) * 16 * 32);
      __builtin_amdgcn_s_setprio(1);
#pragma unroll
      for (int gg = 0; gg < 4; ++gg)
        acc[2 * pr][gg] = __builtin_amdgcn_mfma_f32_16x16x32_bf16(
            afa, bcur[gg], acc[2 * pr][gg], 0, 0, 0);
#pragma unroll
      for (int gg = 0; gg < 4; ++gg)
        acc[2 * pr + 1][gg] = __builtin_amdgcn_mfma_f32_16x16x32_bf16(
            afb, bcur[gg], acc[2 * pr + 1][gg], 0, 0, 0);
      __builtin_amdgcn_s_setprio(0);
    }
    // (4) half1 stage write (loads have landed by now)
    {
      uint4 pk;
      pk.x = cvtpk(f0.x, f0.y);
      pk.y = cvtpk(f0.z, f0.w);
      pk.z = cvtpk(f1.x, f1.y);
      pk.w = cvtpk(f1.z, f1.w);
      const int kcl = sel2 * 4 + (oct >> 2);
      const int kcg = 8 + kcl;
      const int srw = (srow & 3) ^ ((srow >> 2) & 3);
      const int ph = (oct & 3) ^ srw ^ ((kcg >> 2) & 3);
      *(uint4*)&Abuf[1][(kcl * 128 + srow) * 32 + ph * 8] = pk;
    }
#pragma unroll
    for (int gg = 0; gg < 4; ++gg) bcur[gg] = bnxt[gg];
  }

  __syncthreads();  // buf1 complete

  // ---- K2: kc 8..15 on buf1 ----
#pragma unroll
  for (int gg = 0; gg < 4; ++gg)
    bcur[gg] = *(const bf16x8*)(Wq + (8u * 32768u + offb[gg]));
#pragma unroll
  for (int kc = 8; kc < 16; ++kc) {
    if (kc < 15) {
      const u32 kb = (u32)(kc + 1) * 32768u;
#pragma unroll
      for (int gg = 0; gg < 4; ++gg)
        bnxt[gg] = *(const bf16x8*)(Wq + (kb + offb[gg]));
    }
    const int pa = (quad ^ sl ^ ((kc >> 2) & 3)) * 8;
    const u16* ab = &Abuf[1][((kc - 8) * 128 + l15) * 32 + pa];
#pragma unroll
    for (int pr = 0; pr < 4; ++pr) {
      bf16x8 afa = *(const bf16x8*)(ab + (2 * pr) * 16 * 32);
      bf16x8 afb = *(const bf16x8*)(ab + (2 * pr + 1) * 16 * 32);
      __builtin_amdgcn_s_setprio(1);
#pragma unroll
      for (int gg = 0; gg < 4; ++gg)
        acc[2 * pr][gg] = __builtin_amdgcn_mfma_f32_16x16x32_bf16(
            afa, bcur[gg], acc[2 * pr][gg], 0, 0, 0);
#pragma unroll
      for (int gg = 0; gg < 4; ++gg)
        acc[2 * pr + 1][gg] = __builtin_amdgcn_mfma_f32_16x16x32_bf16(
            afb, bcur[gg], acc[2 * pr + 1][gg], 0, 0, 0);
      __builtin_amdgcn_s_setprio(0);
    }
#pragma unroll
    for (int gg = 0; gg < 4; ++gg) bcur[gg] = bnxt[gg];
  }

  // ---- epilogue: tanh / sigmoid / softmax-of-3 / weighted state sum ----
  const float* bcq = bcat + q * 512;
  const float* beq = bexp + q * 384;
  const size_t outbase = (size_t)((q * 32 + b) * 512 + s_base) * HH;
  const int h = wave * 16 + l15;  // 0..127
  const float bc0 = bcq[h];
  const float bc1 = bcq[128 + h];
  const float bc2 = bcq[256 + h];
  const float bc3 = bcq[384 + h];
  const float be1 = beq[h];
  const float be2 = beq[128 + h];
  const float be3 = beq[256 + h];
  const int slot_e = 4 + (h >> 5);  // exper: kc_global 12..15 -> buf1 slot 4..7
  const int oh = (h >> 3) & 3;
  const int he = h & 7;
  const float* cnnb =
      CNN + (size_t)(b * 2048 + q * 512 + s_base) * HH + h;  // fp32, L2-hot
#pragma unroll
  for (int rt = 0; rt < 8; ++rt) {
#pragma unroll
    for (int r = 0; r < 4; ++r) {
      const int row = rt * 16 + quad * 4 + r;
      const int srw = (row & 3) ^ ((row >> 2) & 3);
      const float cnn = cnnb[(size_t)row * HH];
      const float ex =
          bf2f(Abuf[1][(slot_e * 128 + row) * 32 + (oh ^ srw ^ 3) * 8 + he]);
      const float c0 = acc[rt][0][r] + bc0;
      const float p1 = acc[rt][1][r] + bc1 + be1;
      const float p2 = acc[rt][2][r] + bc2 + be2;
      const float p3 = acc[rt][3][r] + bc3 + be3;
      const float e2c = __expf(2.f * c0);
      const float ns = 1.f - 2.f * __builtin_amdgcn_rcpf(e2c + 1.f);  // tanh
      const float g1 = __builtin_amdgcn_rcpf(1.f + __expf(-p1));
      const float g2 = __builtin_amdgcn_rcpf(1.f + __expf(-p2));
      const float g3 = __builtin_amdgcn_rcpf(1.f + __expf(-p3));
      const float e1 = __expf(g1);
      const float e2 = __expf(g2);
      const float e3 = __expf(g3);
      const float inv = __builtin_amdgcn_rcpf(e1 + e2 + e3);
      out[outbase + (size_t)row * HH + h] = (e1 * ns + e2 * cnn + e3 * ex) * inv;
    }
  }
}

extern "C" void kernel_launch(void* const* d_in, const int* in_sizes, int n_in,
                              void* d_out, int out_size, void* d_ws, size_t ws_size,
                              hipStream_t stream) {
  const float* CNN = (const float*)d_in[0];
  const float* gaz = (const float*)d_in[1];
  const float* gazb = (const float*)d_in[2];
  const float* gm = (const float*)d_in[3];
  const float* exper = (const float*)d_in[4];
  const float* Wcat = (const float*)d_in[5];
  const float* bcat = (const float*)d_in[6];
  const float* Wexp = (const float*)d_in[7];
  const float* bexp = (const float*)d_in[8];
  u16* Wc = (u16*)d_ws;  // 2 MB fused bf16 weights

  prep_w<<<512, 256, 0, stream>>>(Wcat, Wexp, Wc);
  fused_gate<<<512, 512, 0, stream>>>(CNN, gaz, gazb, gm, exper, Wc, bcat,
                                      bexp, (float*)d_out);
}